// Round 8
// baseline (7122.435 us; speedup 1.0000x reference)
//
#include <hip/hip_runtime.h>
#include <hip/hip_bf16.h>
#include <math.h>

// Seq2seq GRU (r,z,n), H=1024, L=2, S=T=512, V=32000.
// Round 8: WAVE-AUTONOMOUS recurrence (zero barriers / zero LDS in hot loop).
//   256 WGs x 256 thr; role = bid>>7 (0: layer0, 1: layer1); WG owns 8 elements,
//   each WAVE owns 2 (12 weight rows in reg, 192 VGPR). Per step each wave:
//     poll own-chain h_{t-1} (16 tagged u64/lane) -> 6 Whh dots ->
//     x operand (role0: plain load; role1: poll h^L0_t) -> 6 Wih dots ->
//     butterfly -> gates via static lane-selects -> 2 tagged publishes.
//   No __syncthreads in the loop: waves run as 512 independent engines.
//   L0/L1 run concurrently (lag 1) -> ~1026 serial hops total.
//   All spins bounded -> NaN fill (visible failure, never a hang).
// Then: gemm_out (SIMT f32) + log_softmax_inplace on d_out.

#define HID 1024
#define NSTEP 512
#define VOCAB 32000
#define SPIN_LIMIT 50000
typedef unsigned long long u64;
typedef unsigned int u32;

__device__ __forceinline__ u64 ald(const u64* p) {
    return __hip_atomic_load(p, __ATOMIC_RELAXED, __HIP_MEMORY_SCOPE_AGENT);
}
__device__ __forceinline__ void ast(u64* p, u64 v) {
    __hip_atomic_store(p, v, __ATOMIC_RELAXED, __HIP_MEMORY_SCOPE_AGENT);
}
__device__ __forceinline__ u64 pack_hv(float v, u32 tag) {
    return ((u64)tag << 32) | (u64)__float_as_uint(v);
}
__device__ __forceinline__ float payload(u64 v) {
    return __uint_as_float((u32)(v & 0xffffffffu));
}

// Per-lane: poll 16 tagged pairs row[q*64+lane] until all tags == want; payloads
// into v[16]. Bounded: on give-up fill NaN (diagnostic channel).
__device__ __forceinline__ void poll16(const u64* __restrict__ row, u32 want,
                                       float* v, int lane) {
    u64 p[16];
    int iter = 0;
    for (;;) {
        bool ok = true;
#pragma unroll
        for (int q = 0; q < 16; ++q) {
            p[q] = ald(row + q * 64 + lane);
            ok = ok && ((u32)(p[q] >> 32) == want);
        }
        if (ok) break;
        if (++iter >= SPIN_LIMIT) {
#pragma unroll
            for (int q = 0; q < 16; ++q) v[q] = __uint_as_float(0x7fc00000u);
            return;
        }
    }
#pragma unroll
    for (int q = 0; q < 16; ++q) v[q] = payload(p[q]);
}

// ---------------------------------------------------------------- embeddings
__global__ __launch_bounds__(256) void gather_embed(
    const int* __restrict__ src_tok, const int* __restrict__ tgt_tok,
    const float* __restrict__ src_emb, const float* __restrict__ tgt_emb,
    float* __restrict__ enc_x, float* __restrict__ dec_x) {
    int b = blockIdx.x, tid = threadIdx.x;
    int tok;
    const float* src;
    float* dst;
    if (b < 512) {
        tok = src_tok[b];
        src = src_emb;
        dst = enc_x + (size_t)b * HID;
    } else {
        int t = b - 512;
        tok = (t == 0) ? 0 : tgt_tok[t - 1];  // BOS = 0
        src = tgt_emb;
        dst = dec_x + (size_t)t * HID;
    }
    float4 v = *(const float4*)(src + (size_t)tok * HID + tid * 4);
    *(float4*)(dst + tid * 4) = v;
}

// ---------------------------------------------------------------- recurrence
// Wave owns elements jw, jw+1 (jw = bid&127)*8 + wave*2). wreg idx = e*6+m:
// m 0..2 = Wih gate r,z,n row of element jw+e; m 3..5 = Whh gate rows.
__global__ __launch_bounds__(256, 1) void gru_persist(
    const float* __restrict__ enc_x, const float* __restrict__ dec_x,
    const float* __restrict__ eWih, const float* __restrict__ eWhh,
    const float* __restrict__ eBih, const float* __restrict__ eBhh,
    const float* __restrict__ dWih, const float* __restrict__ dWhh,
    const float* __restrict__ dBih, const float* __restrict__ dBhh,
    u64* H0, u64* H1, u64* D0, u64* D1, float* __restrict__ D1f) {
    const int tid = threadIdx.x;
    const int wave = tid >> 6, lane = tid & 63;
    const int role = blockIdx.x >> 7;
    const int jw = (blockIdx.x & 127) * 8 + wave * 2;
    const int jsel = jw + (lane & 1);  // element this lane's gate math refers to

    float wreg[12][16];
    float hprev = 0.f;  // lanes 0,1: own element's h, carried across steps/phases

#pragma unroll 1
    for (int p = 0; p < 2; ++p) {
        const float* Wih = (p ? dWih : eWih) + (size_t)role * 3 * HID * HID;
        const float* Whh = (p ? dWhh : eWhh) + (size_t)role * 3 * HID * HID;
        const float* bih = (p ? dBih : eBih) + (size_t)role * 3 * HID;
        const float* bhh = (p ? dBhh : eBhh) + (size_t)role * 3 * HID;
        u64* hch = p ? (role ? D1 : D0) : (role ? H1 : H0);
        const u32 tagOut = p ? (role ? 4u : 3u) : (role ? 2u : 1u);
        u64* prevch = role ? H1 : H0;           // own enc chain (dec t=0 init)
        const u32 tagPrev = role ? 2u : 1u;
        const float* xf = p ? dec_x : enc_x;    // role0 x source
        const u64* xt = p ? D0 : H0;            // role1 x source (L0 live)
        const u32 tagX = p ? 3u : 1u;

        // ---- stage 12 rows (6 Wih + 6 Whh for 2 elements) into registers
#pragma unroll
        for (int e = 0; e < 2; ++e)
#pragma unroll
            for (int m = 0; m < 6; ++m) {
                int g = (m < 3) ? m : m - 3;
                const float* base = ((m < 3) ? Wih : Whh) +
                                    (size_t)(g * HID + jw + e) * HID;
#pragma unroll
                for (int q = 0; q < 16; ++q)
                    wreg[e * 6 + m][q] = base[q * 64 + lane];
            }
        const float bIR = bih[jsel], bIZ = bih[HID + jsel], bIN = bih[2 * HID + jsel];
        const float bHR = bhh[jsel], bHZ = bhh[HID + jsel], bHN = bhh[2 * HID + jsel];

#pragma unroll 1
        for (int t = 0; t < NSTEP; ++t) {
            float part[12] = {0.f, 0.f, 0.f, 0.f, 0.f, 0.f,
                              0.f, 0.f, 0.f, 0.f, 0.f, 0.f};
            // ---- own-chain h_{t-1} (ready first), then 6 Whh dots
            {
                float h[16];
                if (t == 0 && p == 0) {
#pragma unroll
                    for (int q = 0; q < 16; ++q) h[q] = 0.f;
                } else {
                    const u64* src = (t > 0) ? (hch + (size_t)(t - 1) * HID)
                                             : (prevch + (size_t)(NSTEP - 1) * HID);
                    poll16(src, (t > 0) ? tagOut : tagPrev, h, lane);
                }
#pragma unroll
                for (int q = 0; q < 16; ++q) {
                    float hq = h[q];
#pragma unroll
                    for (int e = 0; e < 2; ++e)
#pragma unroll
                        for (int m = 3; m < 6; ++m)
                            part[e * 6 + m] = fmaf(wreg[e * 6 + m][q], hq,
                                                   part[e * 6 + m]);
                }
            }
            // ---- x_t (published one lag earlier for role1), then 6 Wih dots
            {
                float x[16];
                if (role == 0) {
                    const float* xr = xf + (size_t)t * HID;
#pragma unroll
                    for (int q = 0; q < 16; ++q) x[q] = xr[q * 64 + lane];
                } else {
                    poll16(xt + (size_t)t * HID, tagX, x, lane);
                }
#pragma unroll
                for (int q = 0; q < 16; ++q) {
                    float xq = x[q];
#pragma unroll
                    for (int e = 0; e < 2; ++e)
#pragma unroll
                        for (int m = 0; m < 3; ++m)
                            part[e * 6 + m] = fmaf(wreg[e * 6 + m][q], xq,
                                                   part[e * 6 + m]);
                }
            }
            // ---- butterfly reduce (all 12 rows)
#pragma unroll
            for (int off = 1; off < 64; off <<= 1)
#pragma unroll
                for (int rr = 0; rr < 12; ++rr)
                    part[rr] += __shfl_xor(part[rr], off);

            // ---- gates: all lanes compute via STATIC selects (lane&1 picks e)
            const bool e1 = (lane & 1) != 0;
            float ir = (e1 ? part[6] : part[0]) + bIR;
            float iz = (e1 ? part[7] : part[1]) + bIZ;
            float in_ = (e1 ? part[8] : part[2]) + bIN;
            float hr = (e1 ? part[9] : part[3]) + bHR;
            float hz = (e1 ? part[10] : part[4]) + bHZ;
            float hn = (e1 ? part[11] : part[5]) + bHN;
            float rg = 1.f / (1.f + __expf(-(ir + hr)));
            float zg = 1.f / (1.f + __expf(-(iz + hz)));
            float na = in_ + rg * hn;
            float ng = 2.f / (1.f + __expf(-2.f * na)) - 1.f;  // tanh
            float hnew = (1.f - zg) * ng + zg * hprev;
            hprev = hnew;
            if (lane < 2) {
                ast(hch + (size_t)t * HID + jsel, pack_hv(hnew, tagOut));
                if (p && role) D1f[(size_t)t * HID + jsel] = hnew;
            }
        }
    }
}

// ---------------------------------------------------------------- GEMM
// C[i][v] = sum_k A[i][k]*B[v][k] + bias[v].  A:[512][1024]  B:[N][1024]
__global__ __launch_bounds__(256) void gemm_out(
    const float* __restrict__ A, const float* __restrict__ B,
    const float* __restrict__ bias, float* __restrict__ C, int ldc) {
    const int tid = threadIdx.x;
    const int bi = blockIdx.x;
    const int bv = blockIdx.y;
    const int i0 = bi * 64, v0 = bv * 128;
    __shared__ __align__(16) float As[32 * 68];
    __shared__ __align__(16) float Bs[32 * 132];
    const int tr = tid >> 4, tc = tid & 15;
    float c[4][8] = {};

    for (int kk = 0; kk < HID; kk += 32) {
#pragma unroll
        for (int q = 0; q < 2; q++) {
            int id = tid * 2 + q;  // 0..511
            int r = id >> 3, kq = id & 7;
            float4 a = *(const float4*)&A[(size_t)(i0 + r) * HID + kk + kq * 4];
            As[(kq * 4 + 0) * 68 + r] = a.x;
            As[(kq * 4 + 1) * 68 + r] = a.y;
            As[(kq * 4 + 2) * 68 + r] = a.z;
            As[(kq * 4 + 3) * 68 + r] = a.w;
        }
#pragma unroll
        for (int q = 0; q < 4; q++) {
            int id = tid * 4 + q;  // 0..1023
            int vr = id >> 3, kq = id & 7;
            float4 b = *(const float4*)&B[(size_t)(v0 + vr) * HID + kk + kq * 4];
            Bs[(kq * 4 + 0) * 132 + vr] = b.x;
            Bs[(kq * 4 + 1) * 132 + vr] = b.y;
            Bs[(kq * 4 + 2) * 132 + vr] = b.z;
            Bs[(kq * 4 + 3) * 132 + vr] = b.w;
        }
        __syncthreads();
#pragma unroll
        for (int k = 0; k < 32; k++) {
            float4 a4 = *(const float4*)&As[k * 68 + tr * 4];
            float4 b0 = *(const float4*)&Bs[k * 132 + tc * 8];
            float4 b1 = *(const float4*)&Bs[k * 132 + tc * 8 + 4];
            float av[4] = {a4.x, a4.y, a4.z, a4.w};
            float bvv[8] = {b0.x, b0.y, b0.z, b0.w, b1.x, b1.y, b1.z, b1.w};
#pragma unroll
            for (int u = 0; u < 4; u++)
#pragma unroll
                for (int w = 0; w < 8; w++) c[u][w] += av[u] * bvv[w];
        }
        __syncthreads();
    }
    float4 bb0 = *(const float4*)&bias[v0 + tc * 8];
    float4 bb1 = *(const float4*)&bias[v0 + tc * 8 + 4];
#pragma unroll
    for (int u = 0; u < 4; u++) {
        int i = i0 + tr * 4 + u;
        float4 o0 = {c[u][0] + bb0.x, c[u][1] + bb0.y, c[u][2] + bb0.z, c[u][3] + bb0.w};
        float4 o1 = {c[u][4] + bb1.x, c[u][5] + bb1.y, c[u][6] + bb1.z, c[u][7] + bb1.w};
        *(float4*)&C[(size_t)i * ldc + v0 + tc * 8] = o0;
        *(float4*)&C[(size_t)i * ldc + v0 + tc * 8 + 4] = o1;
    }
}

// ---------------------------------------------------------------- log-softmax
__global__ __launch_bounds__(256) void log_softmax_inplace(float* __restrict__ C) {
    const int row = blockIdx.x;
    const int tid = threadIdx.x;
    float* p = C + (size_t)row * VOCAB;
    float m = -3.4e38f, s = 0.f;
    for (int idx = tid; idx < VOCAB / 4; idx += 256) {
        float4 x = ((const float4*)p)[idx];
        float xv[4] = {x.x, x.y, x.z, x.w};
#pragma unroll
        for (int u = 0; u < 4; u++) {
            float nm = fmaxf(m, xv[u]);
            s = s * __expf(m - nm) + __expf(xv[u] - nm);
            m = nm;
        }
    }
#pragma unroll
    for (int off = 1; off < 64; off <<= 1) {
        float om = __shfl_xor(m, off);
        float os = __shfl_xor(s, off);
        float nm = fmaxf(m, om);
        s = s * __expf(m - nm) + os * __expf(om - nm);
        m = nm;
    }
    __shared__ float sm[4], ss[4], sL;
    int wv = tid >> 6;
    if ((tid & 63) == 0) { sm[wv] = m; ss[wv] = s; }
    __syncthreads();
    if (tid == 0) {
        float M = sm[0], S = ss[0];
        for (int w = 1; w < 4; w++) {
            float nm = fmaxf(M, sm[w]);
            S = S * __expf(M - nm) + ss[w] * __expf(sm[w] - nm);
            M = nm;
        }
        sL = M + logf(S);
    }
    __syncthreads();
    float L = sL;
    for (int idx = tid; idx < VOCAB / 4; idx += 256) {
        float4 x = ((const float4*)p)[idx];
        x.x -= L; x.y -= L; x.z -= L; x.w -= L;
        ((float4*)p)[idx] = x;
    }
}

// ---------------------------------------------------------------- launcher
extern "C" void kernel_launch(void* const* d_in, const int* in_sizes, int n_in,
                              void* d_out, int out_size, void* d_ws, size_t ws_size,
                              hipStream_t stream) {
    const int* src_tok = (const int*)d_in[0];
    const int* tgt_tok = (const int*)d_in[1];
    const float* src_emb = (const float*)d_in[2];
    const float* tgt_emb = (const float*)d_in[3];
    const float* eWih = (const float*)d_in[4];
    const float* eWhh = (const float*)d_in[5];
    const float* eBih = (const float*)d_in[6];
    const float* eBhh = (const float*)d_in[7];
    const float* dWih = (const float*)d_in[8];
    const float* dWhh = (const float*)d_in[9];
    const float* dBih = (const float*)d_in[10];
    const float* dBhh = (const float*)d_in[11];
    const float* out_W = (const float*)d_in[12];
    const float* out_b = (const float*)d_in[13];
    float* out = (float*)d_out;

    char* ws = (char*)d_ws;
    // layout: enc_x 0-2MiB | dec_x 2-4 | H0 4-8 | H1 8-12 | D0 12-16 | D1 16-20 |
    //         D1f 20-22
    float* enc_x = (float*)(ws);
    float* dec_x = (float*)(ws + (2ull << 20));
    u64* H0 = (u64*)(ws + (4ull << 20));
    u64* H1 = (u64*)(ws + (8ull << 20));
    u64* D0 = (u64*)(ws + (12ull << 20));
    u64* D1 = (u64*)(ws + (16ull << 20));
    float* D1f = (float*)(ws + (20ull << 20));

    // Clear sync tags every launch: stale/poisoned tags must never match (tags 1..4).
    hipMemsetAsync(ws + (4ull << 20), 0, 16ull << 20, stream);

    gather_embed<<<1024, 256, 0, stream>>>(src_tok, tgt_tok, src_emb, tgt_emb,
                                           enc_x, dec_x);
    gru_persist<<<256, 256, 0, stream>>>(enc_x, dec_x, eWih, eWhh, eBih, eBhh,
                                         dWih, dWhh, dBih, dBhh, H0, H1, D0, D1, D1f);
    gemm_out<<<dim3(8, 250), 256, 0, stream>>>(D1f, out_W, out_b, out, VOCAB);
    log_softmax_inplace<<<512, 256, 0, stream>>>(out);
}

// Round 9
// 3487.174 us; speedup vs baseline: 2.0425x; 2.0425x over previous
//
#include <hip/hip_runtime.h>
#include <hip/hip_bf16.h>
#include <math.h>

// Seq2seq GRU (r,z,n), H=1024, L=2, S=T=512, V=32000.
// Round 9: r4 recurrence restored EXACTLY (best of 6 sync structures, 3360us)
//   + bf16-MFMA output projection:
//     - gru gate lanes also emit D1b (bf16) alongside D1f (f32) [off crit path]
//     - cast_w: out_W f32 -> bf16 (once per launch)
//     - gemm_mfma: C = D1b @ Wb^T + bias via mfma_f32_16x16x32_bf16,
//       64x256 block tile, 4 waves, no LDS (W is L3-resident).
//   Wb needs 64MiB of ws beyond the proven 48MiB -> runtime ws_size check with
//   SIMT-f32 fallback (exact r4 path).

#define HID 1024
#define NSTEP 512
#define VOCAB 32000
#define SPIN_LIMIT 50000
typedef unsigned long long u64;
typedef unsigned int u32;

__device__ __forceinline__ u64 pack_hv(float v, u32 tag) {
    return ((u64)tag << 32) | (u64)__float_as_uint(v);
}
__device__ __forceinline__ u32 bf16_rtne(float f) {
    u32 x = __float_as_uint(f);
    return (x + 0x7fffu + ((x >> 16) & 1u)) >> 16;
}

// Per-lane: poll 16 tagged pairs row[q*64+lane] until all tags == want; payloads
// into v[16]. Bounded: on give-up fill NaN (diagnostic channel).
__device__ __forceinline__ void poll16(const u64* __restrict__ row, u32 want,
                                       float* v, int lane) {
    u64 p[16];
    int iter = 0;
    for (;;) {
        bool ok = true;
#pragma unroll
        for (int q = 0; q < 16; ++q) {
            p[q] = __hip_atomic_load((u64*)(row + q * 64 + lane),
                                     __ATOMIC_RELAXED, __HIP_MEMORY_SCOPE_AGENT);
            ok = ok && ((u32)(p[q] >> 32) == want);
        }
        if (ok) break;
        if (++iter >= SPIN_LIMIT) {
#pragma unroll
            for (int q = 0; q < 16; ++q) v[q] = __uint_as_float(0x7fc00000u);
            return;
        }
        __builtin_amdgcn_s_sleep(1);
    }
#pragma unroll
    for (int q = 0; q < 16; ++q)
        v[q] = __uint_as_float((u32)(p[q] & 0xffffffffu));
}

// ---------------------------------------------------------------- embeddings
__global__ __launch_bounds__(256) void gather_embed(
    const int* __restrict__ src_tok, const int* __restrict__ tgt_tok,
    const float* __restrict__ src_emb, const float* __restrict__ tgt_emb,
    float* __restrict__ enc_x, float* __restrict__ dec_x) {
    int b = blockIdx.x, tid = threadIdx.x;
    int tok;
    const float* src;
    float* dst;
    if (b < 512) {
        tok = src_tok[b];
        src = src_emb;
        dst = enc_x + (size_t)b * HID;
    } else {
        int t = b - 512;
        tok = (t == 0) ? 0 : tgt_tok[t - 1];  // BOS = 0
        src = tgt_emb;
        dst = dec_x + (size_t)t * HID;
    }
    float4 v = *(const float4*)(src + (size_t)tok * HID + tid * 4);
    *(float4*)(dst + tid * 4) = v;
}

// ---------------------------------------------------------------- f32 -> bf16
__global__ __launch_bounds__(256) void cast_w(const float* __restrict__ W,
                                              unsigned short* __restrict__ Wb) {
    size_t base = ((size_t)blockIdx.x * 256 + threadIdx.x) * 8;
    const float4* s = (const float4*)(W + base);
    float4 f0 = s[0], f1 = s[1];
    uint4 o;
    o.x = bf16_rtne(f0.x) | (bf16_rtne(f0.y) << 16);
    o.y = bf16_rtne(f0.z) | (bf16_rtne(f0.w) << 16);
    o.z = bf16_rtne(f1.x) | (bf16_rtne(f1.y) << 16);
    o.w = bf16_rtne(f1.z) | (bf16_rtne(f1.w) << 16);
    *(uint4*)(Wb + base) = o;
}

// ---------------------------------------------------------------- recurrence
// r4 structure verbatim: 256 WGs x 256 thr; role = bid>>7; WG owns 8 elements.
// Waves 0-1: Wih rows vs x; waves 2-3: Whh rows vs h. Gates on tid<8.
__global__ __launch_bounds__(256, 1) void gru_persist(
    const float* __restrict__ enc_x, const float* __restrict__ dec_x,
    const float* __restrict__ eWih, const float* __restrict__ eWhh,
    const float* __restrict__ eBih, const float* __restrict__ eBhh,
    const float* __restrict__ dWih, const float* __restrict__ dWhh,
    const float* __restrict__ dBih, const float* __restrict__ dBhh,
    u64* H0, u64* H1, u64* D0, u64* D1, float* __restrict__ D1f,
    unsigned short* __restrict__ D1b) {
    const int tid = threadIdx.x;
    const int wave = tid >> 6, lane = tid & 63;
    const int role = blockIdx.x >> 7;
    const int wl = blockIdx.x & 127;
    const int j0 = wl * 8;

    __shared__ float dots[48];
    __shared__ float sbias[48];

    float wreg[12][16];
    float hprev = 0.f;

#pragma unroll 1
    for (int phase = 0; phase < 2; ++phase) {
        const bool dec = (phase == 1);
        const float* Wih = (dec ? dWih : eWih) + (size_t)role * 3 * HID * HID;
        const float* Whh = (dec ? dWhh : eWhh) + (size_t)role * 3 * HID * HID;
        const float* bih = (dec ? dBih : eBih) + (size_t)role * 3 * HID;
        const float* bhh = (dec ? dBhh : eBhh) + (size_t)role * 3 * HID;
        u64* hch = dec ? (role ? D1 : D0) : (role ? H1 : H0);
        const u32 tagOut = dec ? (role ? 4u : 3u) : (role ? 2u : 1u);
        const float* xf = dec ? dec_x : enc_x;
        const u64* xt = dec ? D0 : H0;
        const u32 tagX = dec ? 3u : 1u;
        const u64* hinit = role ? (H1 + (size_t)(NSTEP - 1) * HID)
                                : (H0 + (size_t)(NSTEP - 1) * HID);
        const u32 tagInit = role ? 2u : 1u;

        __syncthreads();
#pragma unroll
        for (int r = 0; r < 12; ++r) {
            int R = wave * 12 + r;
            int m = (R < 24) ? R : R - 24;
            const float* base = ((R < 24) ? Wih : Whh) +
                                (size_t)((m >> 3) * HID + j0 + (m & 7)) * HID;
#pragma unroll
            for (int q = 0; q < 16; ++q) wreg[r][q] = base[q * 64 + lane];
        }
        if (tid < 48) {
            int m = (tid < 24) ? tid : tid - 24;
            sbias[tid] = ((tid < 24) ? bih : bhh)[(m >> 3) * HID + j0 + (m & 7)];
        }
        __syncthreads();

#pragma unroll 1
        for (int t = 0; t < NSTEP; ++t) {
            float v[16];
            if (wave < 2) {
                if (role == 0) {
                    const float* xr = xf + (size_t)t * HID;
#pragma unroll
                    for (int q = 0; q < 16; ++q) v[q] = xr[q * 64 + lane];
                } else {
                    poll16(xt + (size_t)t * HID, tagX, v, lane);
                }
            } else {
                if (t > 0) {
                    poll16(hch + (size_t)(t - 1) * HID, tagOut, v, lane);
                } else if (dec) {
                    poll16(hinit, tagInit, v, lane);
                } else {
#pragma unroll
                    for (int q = 0; q < 16; ++q) v[q] = 0.f;
                }
            }

            float part[12];
#pragma unroll
            for (int r = 0; r < 12; ++r) {
                float a = 0.f;
#pragma unroll
                for (int q = 0; q < 16; ++q) a = fmaf(wreg[r][q], v[q], a);
                part[r] = a;
            }
#pragma unroll
            for (int off = 1; off < 64; off <<= 1) {
#pragma unroll
                for (int r = 0; r < 12; ++r) part[r] += __shfl_xor(part[r], off);
            }
            if (lane == 0) {
#pragma unroll
                for (int r = 0; r < 12; ++r) dots[wave * 12 + r] = part[r];
            }
            __syncthreads();

            if (tid < 8) {
                const int jj = tid;
                float ir = dots[jj] + sbias[jj];
                float iz = dots[8 + jj] + sbias[8 + jj];
                float in_ = dots[16 + jj] + sbias[16 + jj];
                float hr = dots[24 + jj] + sbias[24 + jj];
                float hz = dots[32 + jj] + sbias[32 + jj];
                float hn = dots[40 + jj] + sbias[40 + jj];
                float rg = 1.f / (1.f + __expf(-(ir + hr)));
                float zg = 1.f / (1.f + __expf(-(iz + hz)));
                float na = in_ + rg * hn;
                float ng = 2.f / (1.f + __expf(-2.f * na)) - 1.f;  // tanh
                float hnew = (1.f - zg) * ng + zg * hprev;
                hprev = hnew;
                __hip_atomic_store((u64*)(hch + (size_t)t * HID + j0 + jj),
                                   pack_hv(hnew, tagOut),
                                   __ATOMIC_RELAXED, __HIP_MEMORY_SCOPE_AGENT);
                if (dec && role == 1) {
                    D1f[(size_t)t * HID + j0 + jj] = hnew;
                    D1b[(size_t)t * HID + j0 + jj] = (unsigned short)bf16_rtne(hnew);
                }
            }
            __syncthreads();
        }
    }
}

// ---------------------------------------------------------------- MFMA GEMM
// C[i][v] = sum_k A[i][k]*B[v][k] + bias[v]; A,B bf16 K-major; C f32.
// Block: 64 (M) x 256 (N); 4 waves, wave w covers n0=w*64; no LDS (B L3-hot).
// mfma_f32_16x16x32_bf16: a/b lane: row/col = lane&15, k = 8*(lane>>4)+j;
// D: col = lane&15, row = 4*(lane>>4)+reg  [m89-verified].
__global__ __launch_bounds__(256) void gemm_mfma(
    const unsigned short* __restrict__ A, const unsigned short* __restrict__ B,
    const float* __restrict__ bias, float* __restrict__ C) {
    typedef __attribute__((ext_vector_type(8))) short short8;
    typedef __attribute__((ext_vector_type(4))) float f32x4;
    const int lane = threadIdx.x & 63, wave = threadIdx.x >> 6;
    const int i0 = blockIdx.x * 64;
    const int v0 = blockIdx.y * 256 + wave * 64;
    const int r16 = lane & 15, kq = lane >> 4;

    f32x4 acc[4][4] = {};
#pragma unroll 4
    for (int k0 = 0; k0 < HID; k0 += 32) {
        short8 a[4], b[4];
#pragma unroll
        for (int mf = 0; mf < 4; ++mf)
            a[mf] = *(const short8*)(A + (size_t)(i0 + mf * 16 + r16) * HID + k0 +
                                     kq * 8);
#pragma unroll
        for (int nf = 0; nf < 4; ++nf)
            b[nf] = *(const short8*)(B + (size_t)(v0 + nf * 16 + r16) * HID + k0 +
                                     kq * 8);
#pragma unroll
        for (int mf = 0; mf < 4; ++mf)
#pragma unroll
            for (int nf = 0; nf < 4; ++nf)
                acc[mf][nf] = __builtin_amdgcn_mfma_f32_16x16x32_bf16(
                    a[mf], b[nf], acc[mf][nf], 0, 0, 0);
    }
#pragma unroll
    for (int nf = 0; nf < 4; ++nf) {
        float bb = bias[v0 + nf * 16 + r16];
#pragma unroll
        for (int mf = 0; mf < 4; ++mf)
#pragma unroll
            for (int reg = 0; reg < 4; ++reg) {
                int i = i0 + mf * 16 + kq * 4 + reg;
                C[(size_t)i * VOCAB + v0 + nf * 16 + r16] = acc[mf][nf][reg] + bb;
            }
    }
}

// ---------------------------------------------------------------- SIMT GEMM (fallback)
__global__ __launch_bounds__(256) void gemm_out(
    const float* __restrict__ A, const float* __restrict__ B,
    const float* __restrict__ bias, float* __restrict__ C, int ldc) {
    const int tid = threadIdx.x;
    const int bi = blockIdx.x;
    const int bv = blockIdx.y;
    const int i0 = bi * 64, v0 = bv * 128;
    __shared__ __align__(16) float As[32 * 68];
    __shared__ __align__(16) float Bs[32 * 132];
    const int tr = tid >> 4, tc = tid & 15;
    float c[4][8] = {};

    for (int kk = 0; kk < HID; kk += 32) {
#pragma unroll
        for (int q = 0; q < 2; q++) {
            int id = tid * 2 + q;
            int r = id >> 3, kq = id & 7;
            float4 a = *(const float4*)&A[(size_t)(i0 + r) * HID + kk + kq * 4];
            As[(kq * 4 + 0) * 68 + r] = a.x;
            As[(kq * 4 + 1) * 68 + r] = a.y;
            As[(kq * 4 + 2) * 68 + r] = a.z;
            As[(kq * 4 + 3) * 68 + r] = a.w;
        }
#pragma unroll
        for (int q = 0; q < 4; q++) {
            int id = tid * 4 + q;
            int vr = id >> 3, kq = id & 7;
            float4 b = *(const float4*)&B[(size_t)(v0 + vr) * HID + kk + kq * 4];
            Bs[(kq * 4 + 0) * 132 + vr] = b.x;
            Bs[(kq * 4 + 1) * 132 + vr] = b.y;
            Bs[(kq * 4 + 2) * 132 + vr] = b.z;
            Bs[(kq * 4 + 3) * 132 + vr] = b.w;
        }
        __syncthreads();
#pragma unroll
        for (int k = 0; k < 32; k++) {
            float4 a4 = *(const float4*)&As[k * 68 + tr * 4];
            float4 b0 = *(const float4*)&Bs[k * 132 + tc * 8];
            float4 b1 = *(const float4*)&Bs[k * 132 + tc * 8 + 4];
            float av[4] = {a4.x, a4.y, a4.z, a4.w};
            float bvv[8] = {b0.x, b0.y, b0.z, b0.w, b1.x, b1.y, b1.z, b1.w};
#pragma unroll
            for (int u = 0; u < 4; u++)
#pragma unroll
                for (int w = 0; w < 8; w++) c[u][w] += av[u] * bvv[w];
        }
        __syncthreads();
    }
    float4 bb0 = *(const float4*)&bias[v0 + tc * 8];
    float4 bb1 = *(const float4*)&bias[v0 + tc * 8 + 4];
#pragma unroll
    for (int u = 0; u < 4; u++) {
        int i = i0 + tr * 4 + u;
        float4 o0 = {c[u][0] + bb0.x, c[u][1] + bb0.y, c[u][2] + bb0.z, c[u][3] + bb0.w};
        float4 o1 = {c[u][4] + bb1.x, c[u][5] + bb1.y, c[u][6] + bb1.z, c[u][7] + bb1.w};
        *(float4*)&C[(size_t)i * ldc + v0 + tc * 8] = o0;
        *(float4*)&C[(size_t)i * ldc + v0 + tc * 8 + 4] = o1;
    }
}

// ---------------------------------------------------------------- log-softmax
__global__ __launch_bounds__(256) void log_softmax_inplace(float* __restrict__ C) {
    const int row = blockIdx.x;
    const int tid = threadIdx.x;
    float* p = C + (size_t)row * VOCAB;
    float m = -3.4e38f, s = 0.f;
    for (int idx = tid; idx < VOCAB / 4; idx += 256) {
        float4 x = ((const float4*)p)[idx];
        float xv[4] = {x.x, x.y, x.z, x.w};
#pragma unroll
        for (int u = 0; u < 4; u++) {
            float nm = fmaxf(m, xv[u]);
            s = s * __expf(m - nm) + __expf(xv[u] - nm);
            m = nm;
        }
    }
#pragma unroll
    for (int off = 1; off < 64; off <<= 1) {
        float om = __shfl_xor(m, off);
        float os = __shfl_xor(s, off);
        float nm = fmaxf(m, om);
        s = s * __expf(m - nm) + os * __expf(om - nm);
        m = nm;
    }
    __shared__ float sm[4], ss[4], sL;
    int wv = tid >> 6;
    if ((tid & 63) == 0) { sm[wv] = m; ss[wv] = s; }
    __syncthreads();
    if (tid == 0) {
        float M = sm[0], S = ss[0];
        for (int w = 1; w < 4; w++) {
            float nm = fmaxf(M, sm[w]);
            S = S * __expf(M - nm) + ss[w] * __expf(sm[w] - nm);
            M = nm;
        }
        sL = M + logf(S);
    }
    __syncthreads();
    float L = sL;
    for (int idx = tid; idx < VOCAB / 4; idx += 256) {
        float4 x = ((const float4*)p)[idx];
        x.x -= L; x.y -= L; x.z -= L; x.w -= L;
        ((float4*)p)[idx] = x;
    }
}

// ---------------------------------------------------------------- launcher
extern "C" void kernel_launch(void* const* d_in, const int* in_sizes, int n_in,
                              void* d_out, int out_size, void* d_ws, size_t ws_size,
                              hipStream_t stream) {
    const int* src_tok = (const int*)d_in[0];
    const int* tgt_tok = (const int*)d_in[1];
    const float* src_emb = (const float*)d_in[2];
    const float* tgt_emb = (const float*)d_in[3];
    const float* eWih = (const float*)d_in[4];
    const float* eWhh = (const float*)d_in[5];
    const float* eBih = (const float*)d_in[6];
    const float* eBhh = (const float*)d_in[7];
    const float* dWih = (const float*)d_in[8];
    const float* dWhh = (const float*)d_in[9];
    const float* dBih = (const float*)d_in[10];
    const float* dBhh = (const float*)d_in[11];
    const float* out_W = (const float*)d_in[12];
    const float* out_b = (const float*)d_in[13];
    float* out = (float*)d_out;

    char* ws = (char*)d_ws;
    // layout (MiB): enc_x 0-2 | dec_x 2-4 | H0 4-8 | H1 8-12 | D0 12-16 |
    //   D1 16-20 | D1f 20-22 | D1b 22-23 | Wb 23-87 (fast path only)
    float* enc_x = (float*)(ws);
    float* dec_x = (float*)(ws + (2ull << 20));
    u64* H0 = (u64*)(ws + (4ull << 20));
    u64* H1 = (u64*)(ws + (8ull << 20));
    u64* D0 = (u64*)(ws + (12ull << 20));
    u64* D1 = (u64*)(ws + (16ull << 20));
    float* D1f = (float*)(ws + (20ull << 20));
    unsigned short* D1b = (unsigned short*)(ws + (22ull << 20));
    unsigned short* Wb = (unsigned short*)(ws + (23ull << 20));
    const bool fast = ws_size >= (87ull << 20);

    // Clear sync tags every launch: stale/poisoned tags must never match.
    hipMemsetAsync(ws + (4ull << 20), 0, 16ull << 20, stream);

    gather_embed<<<1024, 256, 0, stream>>>(src_tok, tgt_tok, src_emb, tgt_emb,
                                           enc_x, dec_x);
    if (fast) cast_w<<<16000, 256, 0, stream>>>(out_W, Wb);

    gru_persist<<<256, 256, 0, stream>>>(enc_x, dec_x, eWih, eWhh, eBih, eBhh,
                                         dWih, dWhh, dBih, dBhh, H0, H1, D0, D1,
                                         D1f, D1b);

    if (fast)
        gemm_mfma<<<dim3(8, 125), 256, 0, stream>>>(D1b, Wb, out_b, out);
    else
        gemm_out<<<dim3(8, 250), 256, 0, stream>>>(D1f, out_W, out_b, out, VOCAB);
    log_softmax_inplace<<<512, 256, 0, stream>>>(out);
}